// Round 1
// 380.355 us; speedup vs baseline: 1.0020x; 1.0020x over previous
//
#include <hip/hip_runtime.h>

// FeatureSampler: BEVFormer-style multi-cam multi-level bilinear sampling.
// B=2, N=6 cams, C=256 ch, M=900 queries, 4 levels. fp32 in/out.
//
// R1 (direct branchy gather):       390 us
// R2 (fp16 transpose + gather):     484 us
// R3 (fused transpose, bank fix):   474 us
// R4 (float2 pair loads, breaks):   381 us
//
// R5: MLP fix. R4's level loop had a wave-uniform `break` between each
// float2 pair -> only ~2 scattered loads in flight per wave; at ~375ns
// HBM latency that is ~3.6KB in flight per CU vs ~10KB needed to saturate
// -> latency-bound (consistent with R1->R4 halving load count for -9us).
// Here the level loop is fully predicated:
//  - validity regions nest, so ONE level-0 guard replaces the break chain;
//  - per-level validity folds into the bilinear weights (invalid -> 0);
//  - invalid levels alias the level-0 address (same-wave L1 hit, zero
//    extra HBM lines);
// so all 8 loads per cam issue back-to-back (cndmask'd addresses, no
// control flow) -> 4x loads in flight per wave.

static constexpr float EPSV = 1e-5f;
static constexpr int Bn = 2, Nn = 6, Cn = 256, Mn = 900;

static constexpr int Hs[4]  = {116, 58, 29, 15};
static constexpr int Wd[4]  = {200, 100, 50, 25};
static constexpr int HWs[4] = {23200, 5800, 1450, 375};

__global__ __launch_bounds__(256) void FeatureSampler_74062416052404_kernel(
    const float* __restrict__ f0, const float* __restrict__ f1,
    const float* __restrict__ f2, const float* __restrict__ f3,
    const float* __restrict__ refp, const float* __restrict__ l2i,
    float* __restrict__ out)
{
    const int q = blockIdx.x;            // 0..1799, one query per block
    const int b = (q >= Mn) ? 1 : 0;
    const int c = threadIdx.x;           // channel

    const float rx = refp[q * 3 + 0] * 122.4f - 61.2f;
    const float ry = refp[q * 3 + 1] * 122.4f - 61.2f;
    const float rz = refp[q * 3 + 2] * 20.0f  - 10.0f;

    const float* const feats[4] = {f0, f1, f2, f3};
    // per-lane, per-level base for this batch; cam term added per iteration
    const float* fb[4];
    int nStride[4];
#pragma unroll
    for (int l = 0; l < 4; ++l) {
        nStride[l] = Cn * HWs[l];
        fb[l] = feats[l] + (size_t)b * Nn * nStride[l] + c * HWs[l];
    }

    float acc  = 0.0f;
    float wsum = 0.0f;

    for (int n = 0; n < Nn; ++n) {
        const float* L = l2i + (size_t)(b * Nn + n) * 16;
        const float cx = L[0] * rx + L[1] * ry + L[2]  * rz + L[3];
        const float cy = L[4] * rx + L[5] * ry + L[6]  * rz + L[7];
        const float cz = L[8] * rx + L[9] * ry + L[10] * rz + L[11];
        if (!(cz > EPSV)) continue;      // wave-uniform skip, contributes 0/0
        wsum += 1.0f;

        const float inv = 1.0f / (cz + EPSV);
        const float x = cx * inv - 0.5f;  // same pixel coord for every level
        const float y = cy * inv - 0.5f;
        const float x0f = floorf(x), y0f = floorf(y);

        // level-0 any-corner region [-1,200)x[-1,116); levels nest inside it,
        // so if this fails ALL levels fail (cam still counts toward wsum).
        // NaN coords compare false -> skip.
        if (!((x0f >= -1.0f) & (x0f < 200.0f) & (y0f >= -1.0f) & (y0f < 116.0f)))
            continue;

        const float wx1 = x - x0f, wx0 = 1.0f - wx1;
        const float wy1 = y - y0f, wy0 = 1.0f - wy1;
        const int xi0 = (int)x0f;        // exact: x0f in [-1, 200)
        const int yi0 = (int)y0f;
        const float a0 = (xi0 >= 0) ? wx0 : 0.0f;   // shared across levels

        // ---- phase 1: addresses + masked weights for all 4 levels (no CF) ----
        const float* p0[4]; const float* p1[4];
        float A1[4], B0[4], B1[4];
        bool lo[4];
#pragma unroll
        for (int l = 0; l < 4; ++l) {
            const int W = Wd[l], H = Hs[l];
            // lower bounds already guaranteed by the level-0 guard
            const bool v = (l == 0) | ((x0f < (float)W) & (y0f < (float)H));

            const int xp  = min(max(xi0, 0), W - 2);   // safe float2 pair base
            const int y0c = max(yi0, 0);
            const int y1c = min(yi0 + 1, H - 1);
            lo[l] = (xi0 == xp);

            const float* base = fb[l] + n * nStride[l];
            const float* q0 = base + y0c * W + xp;
            const float* q1 = base + y1c * W + xp;
            // invalid level -> alias the level-0 address just issued by this
            // wave: L1 same-line hit, no extra HBM traffic, weights are 0.
            p0[l] = v ? q0 : p0[0];
            p1[l] = v ? q1 : p1[0];

            A1[l] = (v & (xi0 < W - 1)) ? wx1 : 0.0f;
            B0[l] = (v & (yi0 >= 0))    ? wy0 : 0.0f;
            B1[l] = (v & (yi0 < H - 1)) ? wy1 : 0.0f;
        }

        // ---- phase 2: 8 back-to-back loads, all in flight together ----
        float2 r0[4], r1[4];
#pragma unroll
        for (int l = 0; l < 4; ++l) {
            r0[l] = *(const float2*)p0[l];
            r1[l] = *(const float2*)p1[l];
        }

        // ---- phase 3: swizzle + accumulate ----
#pragma unroll
        for (int l = 0; l < 4; ++l) {
            const float v00 = lo[l] ? r0[l].x : r0[l].y;
            const float v01 = lo[l] ? r0[l].y : r0[l].x;
            const float v10 = lo[l] ? r1[l].x : r1[l].y;
            const float v11 = lo[l] ? r1[l].y : r1[l].x;
            acc += (a0 * B0[l]) * v00 + (A1[l] * B0[l]) * v01
                 + (a0 * B1[l]) * v10 + (A1[l] * B1[l]) * v11;
        }
    }

    out[(size_t)q * Cn + c] = acc * 0.25f / (wsum + EPSV);
}

extern "C" void kernel_launch(void* const* d_in, const int* in_sizes, int n_in,
                              void* d_out, int out_size, void* d_ws, size_t ws_size,
                              hipStream_t stream) {
    const float* f0   = (const float*)d_in[0];
    const float* f1   = (const float*)d_in[1];
    const float* f2   = (const float*)d_in[2];
    const float* f3   = (const float*)d_in[3];
    const float* refp = (const float*)d_in[4];
    const float* l2i  = (const float*)d_in[5];
    float* out = (float*)d_out;

    FeatureSampler_74062416052404_kernel<<<dim3(Bn * Mn), dim3(256), 0, stream>>>(
        f0, f1, f2, f3, refp, l2i, out);
}